// Round 1
// baseline (856.775 us; speedup 1.0000x reference)
//
#include <hip/hip_runtime.h>
#include <math.h>

// Problem constants
#define NROWS 32768   // 8*4096 input rows
#define KEMB  8192    // codebook entries
// DIM = 64

#define DECAYF 0.99f
#define OMDF   0.01f   // (1 - 0.99) rounded to f32 == 0.01f

// d_out layout (floats), concatenated in reference return order
#define OUT_Q    0          // quantized, 2097152
#define OUT_LOSS 2097152    // vq_loss, 1
#define OUT_IDX  2097153    // idx (as float), 32768
#define OUT_PERP 2129921    // perplexity, 1
#define OUT_NW   2129922    // new_weight, 524288
#define OUT_NCC  2654210    // new_cc, 8192
#define OUT_NWS  2662402    // new_ws, 524288
// total 3186690

// d_ws layout (4-byte units)
#define WS_N      0
#define WS_ENT    1
#define WS_LOSS   2
#define WS_COUNTS 4                    // 8192 floats (atomic)
#define WS_EMB    8196                 // 524288 floats (atomic)
#define WS_IDX    532484               // 32768 ints
#define WS_W2     565252               // 8192 floats
#define WS_X2     573444               // 32768 floats
#define WS_ZERO_UNITS 532484           // only scalars+counts+emb need zeroing

__device__ __forceinline__ float sq_rn(float v) { return __fmul_rn(v, v); }

// numpy pairwise_sum order for 64 contiguous squared values:
// 8 strided accumulators, then ((a0+a1)+(a2+a3)) + ((a4+a5)+(a6+a7))
__device__ __forceinline__ float npsumsq64(const float* vbuf) {
  float a[8];
#pragma unroll
  for (int j = 0; j < 8; ++j) a[j] = sq_rn(vbuf[j]);
#pragma unroll
  for (int m = 1; m < 8; ++m)
#pragma unroll
    for (int j = 0; j < 8; ++j) a[j] = __fadd_rn(a[j], sq_rn(vbuf[m*8 + j]));
  return __fadd_rn(__fadd_rn(__fadd_rn(a[0],a[1]), __fadd_rn(a[2],a[3])),
                   __fadd_rn(__fadd_rn(a[4],a[5]), __fadd_rn(a[6],a[7])));
}

// Precompute ||w_k||^2 (k<8192) and ||x_r||^2 (rows), numpy-exact order.
__global__ __launch_bounds__(256) void prep_kernel(const float* __restrict__ xg,
                                                   const float* __restrict__ wg,
                                                   float* __restrict__ ws) {
  const int tid = blockIdx.x * 256 + threadIdx.x;  // 0..40959
  const float* src;
  float* dst;
  if (tid < KEMB) { src = wg + (size_t)tid * 64; dst = ws + WS_W2 + tid; }
  else { const int r = tid - KEMB; src = xg + (size_t)r * 64; dst = ws + WS_X2 + r; }
  float vbuf[64];
#pragma unroll
  for (int f = 0; f < 16; ++f) {
    float4 v = *(const float4*)(src + f*4);
    vbuf[f*4+0]=v.x; vbuf[f*4+1]=v.y; vbuf[f*4+2]=v.z; vbuf[f*4+3]=v.w;
  }
  *dst = npsumsq64(vbuf);
}

// Main kernel: per-row argmin over all 8192 codes + EMA segment-sum atomics.
// Block: 128 rows x (loop of 64 chunks of 128 codes). 256 threads, 8x8 tiles.
__global__ __launch_bounds__(256) void argmin_kernel(const float* __restrict__ xg,
                                                     const float* __restrict__ wg,
                                                     float* __restrict__ out,
                                                     float* __restrict__ ws) {
  __shared__ __align__(16) float xT[64*128];  // xT[d][r], 32 KB
  __shared__ __align__(16) float wT[64*128];  // wT[d][c], 32 KB (reused for reduction)

  const int t  = threadIdx.x;
  const int tx = t & 15, ty = t >> 4;
  const int row0 = blockIdx.x * 128;

  // Stage x tile transposed. thread t -> row r=t>>1, half h=t&1 (32 floats).
  {
    const int r = t >> 1, h = t & 1;
    const float* src = xg + (size_t)(row0 + r) * 64 + h * 32;
#pragma unroll
    for (int i = 0; i < 8; ++i) {
      float4 v = *(const float4*)(src + i*4);
      const int d = h*32 + i*4;
      xT[(d+0)*128 + r] = v.x;   // bank = r%32, 2 lanes/bank -> free
      xT[(d+1)*128 + r] = v.y;
      xT[(d+2)*128 + r] = v.z;
      xT[(d+3)*128 + r] = v.w;
    }
  }

  // Register tile: rows {4ty..4ty+3, 64+4ty..}, codes {4tx..4tx+3, 64+4tx..}
  int rI[8], cI[8];
#pragma unroll
  for (int i = 0; i < 4; ++i) { rI[i] = 4*ty + i; rI[i+4] = 64 + 4*ty + i; }
#pragma unroll
  for (int j = 0; j < 4; ++j) { cI[j] = 4*tx + j; cI[j+4] = 64 + 4*tx + j; }

  float x2r[8];
#pragma unroll
  for (int i = 0; i < 8; ++i) x2r[i] = ws[WS_X2 + row0 + rI[i]];

  float best[8]; int bestk[8];
#pragma unroll
  for (int i = 0; i < 8; ++i) { best[i] = INFINITY; bestk[i] = 0; }

  for (int kk = 0; kk < 64; ++kk) {
    const int k0 = kk * 128;
    __syncthreads();  // previous chunk's wT reads complete
    {
      const int c = t >> 1, h = t & 1;
      const float* src = wg + (size_t)(k0 + c) * 64 + h * 32;
#pragma unroll
      for (int i = 0; i < 8; ++i) {
        float4 v = *(const float4*)(src + i*4);
        const int d = h*32 + i*4;
        wT[(d+0)*128 + c] = v.x;
        wT[(d+1)*128 + c] = v.y;
        wT[(d+2)*128 + c] = v.z;
        wT[(d+3)*128 + c] = v.w;
      }
    }
    float w2r[8];
#pragma unroll
    for (int j = 0; j < 8; ++j) w2r[j] = ws[WS_W2 + k0 + cI[j]];
    __syncthreads();

    float acc[64];
#pragma unroll
    for (int i = 0; i < 64; ++i) acc[i] = 0.0f;

#pragma unroll 4
    for (int d = 0; d < 64; ++d) {
      float4 xa = *(const float4*)&xT[d*128 + 4*ty];        // 4 addrs, 16-way bcast
      float4 xb = *(const float4*)&xT[d*128 + 64 + 4*ty];
      float4 wa = *(const float4*)&wT[d*128 + 4*tx];        // 16 addrs, 2-way -> free
      float4 wb = *(const float4*)&wT[d*128 + 64 + 4*tx];
      float xv[8] = {xa.x,xa.y,xa.z,xa.w, xb.x,xb.y,xb.z,xb.w};
      float wv[8] = {wa.x,wa.y,wa.z,wa.w, wb.x,wb.y,wb.z,wb.w};
#pragma unroll
      for (int i = 0; i < 8; ++i)
#pragma unroll
        for (int j = 0; j < 8; ++j)
          acc[i*8+j] = fmaf(xv[i], wv[j], acc[i*8+j]);  // sequential fp32 chain
    }

    // dist = (x2 + w2) - 2*dot, single rounding == numpy's subtract
#pragma unroll
    for (int i = 0; i < 8; ++i)
#pragma unroll
      for (int j = 0; j < 8; ++j) {
        const float dist = fmaf(-2.0f, acc[i*8+j], __fadd_rn(x2r[i], w2r[j]));
        const int kidx = k0 + cI[j];   // j ascending => k ascending
        if (dist < best[i]) { best[i] = dist; bestk[i] = kidx; }  // strict < keeps lowest k
      }
  }

  // Merge across the 16 tx threads sharing each row (lexicographic (d,k))
  __syncthreads();
  float* red_d = wT;                 // 128*16 floats
  int*   red_k = (int*)(wT + 2048);  // 128*16 ints
#pragma unroll
  for (int i = 0; i < 8; ++i) {
    red_d[rI[i]*16 + tx] = best[i];
    red_k[rI[i]*16 + tx] = bestk[i];
  }
  __syncthreads();
  if (t < 128) {
    const int r = t;
    float bd = red_d[r*16]; int bk = red_k[r*16];
#pragma unroll
    for (int u = 1; u < 16; ++u) {
      const float d2 = red_d[r*16 + u]; const int k2 = red_k[r*16 + u];
      if (d2 < bd || (d2 == bd && k2 < bk)) { bd = d2; bk = k2; }
    }
    out[OUT_IDX + row0 + r] = (float)bk;
    ((int*)ws)[WS_IDX + row0 + r] = bk;
    atomicAdd(&ws[WS_COUNTS + bk], 1.0f);
    float* emb = ws + WS_EMB + (size_t)bk * 64;
#pragma unroll 8
    for (int d = 0; d < 64; ++d) atomicAdd(&emb[d], xT[d*128 + r]);  // x still in LDS
  }
}

// new_cc, n = sum(new_cc), entropy for perplexity
__global__ __launch_bounds__(256) void stats_kernel(const float* __restrict__ cc,
                                                    float* __restrict__ out,
                                                    float* __restrict__ ws) {
  const int k = blockIdx.x * 256 + threadIdx.x;
  const float cnt = ws[WS_COUNTS + k];
  const float ncc = __fadd_rn(__fmul_rn(DECAYF, cc[k]), __fmul_rn(OMDF, cnt));
  out[OUT_NCC + k] = ncc;
  const float p = cnt * (1.0f/32768.0f);                 // exact (pow2 divide)
  const float ent = __fmul_rn(p, logf(__fadd_rn(p, 1e-10f)));
  float v1 = ncc, v2 = ent;
#pragma unroll
  for (int off = 32; off > 0; off >>= 1) {
    v1 += __shfl_down(v1, off);
    v2 += __shfl_down(v2, off);
  }
  __shared__ float s1[4], s2[4];
  const int lane = threadIdx.x & 63, wid = threadIdx.x >> 6;
  if (lane == 0) { s1[wid] = v1; s2[wid] = v2; }
  __syncthreads();
  if (threadIdx.x == 0) {
    atomicAdd(&ws[WS_N],   (s1[0]+s1[1]) + (s1[2]+s1[3]));
    atomicAdd(&ws[WS_ENT], (s2[0]+s2[1]) + (s2[2]+s2[3]));
  }
}

// new_ws and new_weight
__global__ __launch_bounds__(256) void update_kernel(const float* __restrict__ ws0,
                                                     float* __restrict__ out,
                                                     float* __restrict__ ws) {
  const int e = blockIdx.x * 256 + threadIdx.x;  // < 524288
  const int k = e >> 6;
  const float nws = __fadd_rn(__fmul_rn(DECAYF, ws0[e]), __fmul_rn(OMDF, ws[WS_EMB + e]));
  out[OUT_NWS + e] = nws;
  const float n = ws[WS_N];
  const float ncc = out[OUT_NCC + k];
  // (new_cc + EPS) / (n + K*EPS) * n, division then multiply (reference order)
  const float smoothed = __fmul_rn(__fadd_rn(ncc, 1e-5f) / __fadd_rn(n, 0.08192f), n);
  out[OUT_NW + e] = nws / smoothed;
}

// quantized (straight-through) + vq_loss partial sums
__global__ __launch_bounds__(256) void quant_kernel(const float* __restrict__ xg,
                                                    float* __restrict__ out,
                                                    float* __restrict__ ws) {
  const int e = blockIdx.x * 256 + threadIdx.x;  // < 2097152
  const int row = e >> 6, d = e & 63;
  const int k = ((const int*)ws)[WS_IDX + row];
  const float q = out[OUT_NW + (size_t)k*64 + d];
  const float x = xg[e];
  const float df = __fsub_rn(q, x);               // stop_grad(q) - x
  out[OUT_Q + e] = __fadd_rn(x, df);              // x + (q - x), reference rounding
  float v = __fmul_rn(df, df);
#pragma unroll
  for (int off = 32; off > 0; off >>= 1) v += __shfl_down(v, off);
  __shared__ float sm[4];
  const int lane = threadIdx.x & 63, wid = threadIdx.x >> 6;
  if (lane == 0) sm[wid] = v;
  __syncthreads();
  if (threadIdx.x == 0) atomicAdd(&ws[WS_LOSS], (sm[0]+sm[1]) + (sm[2]+sm[3]));
}

__global__ void final_kernel(float* __restrict__ out, const float* __restrict__ ws) {
  out[OUT_LOSS] = __fmul_rn(0.25f, ws[WS_LOSS] / 2097152.0f);
  out[OUT_PERP] = expf(-ws[WS_ENT]);
}

extern "C" void kernel_launch(void* const* d_in, const int* in_sizes, int n_in,
                              void* d_out, int out_size, void* d_ws, size_t ws_size,
                              hipStream_t stream) {
  (void)in_sizes; (void)n_in; (void)out_size; (void)ws_size;
  const float* x   = (const float*)d_in[0];  // inputs (8,4096,64)
  const float* w   = (const float*)d_in[1];  // weight (8192,64)
  const float* cc  = (const float*)d_in[2];  // ema_cluster_count (8192,)
  const float* ws0 = (const float*)d_in[3];  // ema_weight_sum (8192,64)
  float* out = (float*)d_out;
  float* ws  = (float*)d_ws;

  hipMemsetAsync(d_ws, 0, (size_t)WS_ZERO_UNITS * 4, stream);
  hipLaunchKernelGGL(prep_kernel,   dim3(160),  dim3(256), 0, stream, x, w, ws);
  hipLaunchKernelGGL(argmin_kernel, dim3(256),  dim3(256), 0, stream, x, w, out, ws);
  hipLaunchKernelGGL(stats_kernel,  dim3(32),   dim3(256), 0, stream, cc, out, ws);
  hipLaunchKernelGGL(update_kernel, dim3(2048), dim3(256), 0, stream, ws0, out, ws);
  hipLaunchKernelGGL(quant_kernel,  dim3(8192), dim3(256), 0, stream, x, out, ws);
  hipLaunchKernelGGL(final_kernel,  dim3(1),    dim3(1),   0, stream, out, ws);
}

// Round 2
// 354.516 us; speedup vs baseline: 2.4167x; 2.4167x over previous
//
#include <hip/hip_runtime.h>
#include <math.h>

typedef _Float16 f16x8 __attribute__((ext_vector_type(8)));
typedef float f32x4 __attribute__((ext_vector_type(4)));

// Problem constants
#define NROWS 32768   // 8*4096 input rows
#define KEMB  8192    // codebook entries
// DIM = 64

#define DECAYF 0.99f
#define OMDF   0.01f

// d_out layout (floats), concatenated in reference return order
#define OUT_Q    0          // quantized, 2097152
#define OUT_LOSS 2097152    // vq_loss, 1
#define OUT_IDX  2097153    // idx (as float), 32768
#define OUT_PERP 2129921    // perplexity, 1
#define OUT_NW   2129922    // new_weight, 524288
#define OUT_NCC  2654210    // new_cc, 8192
#define OUT_NWS  2662402    // new_ws, 524288

// d_ws layout (4-byte units) -- identical to round 1 (known to fit ws_size)
#define WS_N      0
#define WS_ENT    1
#define WS_LOSS   2
#define WS_COUNTS 4                    // 8192 floats (atomic)
#define WS_EMB    8196                 // 524288 floats (atomic)
#define WS_IDX    532484               // 32768 ints
#define WS_W2     565252               // 8192 floats
#define WS_X2     573444               // 32768 floats
#define WS_ZERO_UNITS 532484

__device__ __forceinline__ float sq_rn(float v) { return __fmul_rn(v, v); }

// numpy pairwise_sum order for 64 contiguous squared values
__device__ __forceinline__ float npsumsq64(const float* vbuf) {
  float a[8];
#pragma unroll
  for (int j = 0; j < 8; ++j) a[j] = sq_rn(vbuf[j]);
#pragma unroll
  for (int m = 1; m < 8; ++m)
#pragma unroll
    for (int j = 0; j < 8; ++j) a[j] = __fadd_rn(a[j], sq_rn(vbuf[m*8 + j]));
  return __fadd_rn(__fadd_rn(__fadd_rn(a[0],a[1]), __fadd_rn(a[2],a[3])),
                   __fadd_rn(__fadd_rn(a[4],a[5]), __fadd_rn(a[6],a[7])));
}

__global__ __launch_bounds__(256) void prep_kernel(const float* __restrict__ xg,
                                                   const float* __restrict__ wg,
                                                   float* __restrict__ ws) {
  const int tid = blockIdx.x * 256 + threadIdx.x;  // 0..40959
  const float* src;
  float* dst;
  if (tid < KEMB) { src = wg + (size_t)tid * 64; dst = ws + WS_W2 + tid; }
  else { const int r = tid - KEMB; src = xg + (size_t)r * 64; dst = ws + WS_X2 + r; }
  float vbuf[64];
#pragma unroll
  for (int f = 0; f < 16; ++f) {
    float4 v = *(const float4*)(src + f*4);
    vbuf[f*4+0]=v.x; vbuf[f*4+1]=v.y; vbuf[f*4+2]=v.z; vbuf[f*4+3]=v.w;
  }
  *dst = npsumsq64(vbuf);
}

// split a float into (hi, lo) fp16 pair; hi+lo reproduces x to 22 bits
__device__ __forceinline__ void split_f16(float x, _Float16& hi, _Float16& lo) {
  hi = (_Float16)x;
  float r = __fsub_rn(x, (float)hi);   // exact (Sterbenz)
  lo = (_Float16)r;
}

// MFMA argmin: per block 128 rows, loop 32 chunks of 256 codes.
// 512 threads = 8 waves (2 row-groups x 4 col-groups), wave tile 64x64,
// 16 C-tiles of 16x16x(K=128 split-fp16) = 8 MFMAs each.
__global__ __launch_bounds__(512, 2) void argmin_kernel(const float* __restrict__ xg,
                                                        const float* __restrict__ wg,
                                                        float* __restrict__ out,
                                                        float* __restrict__ ws) {
  // LDS: frag-ready f16 tiles. slot layout [panel][s][lane][8 f16], s: 0,1=hi 2,3=lo
  __shared__ __align__(16) _Float16 xp[8*4*64*8];    // 32 KB
  __shared__ __align__(16) _Float16 wp[16*4*64*8];   // 64 KB
  __shared__ float w2s[256];
  __shared__ float md[128*4];
  __shared__ int   mk[128*4];
  __shared__ int   bkL[128];

  const int t    = threadIdx.x;
  const int lane = t & 63, wv = t >> 6;
  const int quad = lane >> 4, n16 = lane & 15;
  const int rg = wv >> 2, cg = wv & 3;
  const int row0 = blockIdx.x * 128;

  // ---- prologue: convert X tile into fragment layout (once) ----
#pragma unroll
  for (int it = 0; it < 2; ++it) {
    const int u  = t + 512*it;          // < 1024 granules
    const int rp = u >> 7, n = (u >> 3) & 15, g = u & 7;
    const float* src = xg + (size_t)(row0 + rp*16 + n)*64 + g*8;
    float4 v0 = *(const float4*)src, v1 = *(const float4*)(src + 4);
    float vv[8] = {v0.x,v0.y,v0.z,v0.w,v1.x,v1.y,v1.z,v1.w};
    f16x8 hi, lo;
#pragma unroll
    for (int j = 0; j < 8; ++j) { _Float16 h, l; split_f16(vv[j], h, l); hi[j]=h; lo[j]=l; }
    const int slot = (g&3)*16 + n, shi = g >> 2;
    *(f16x8*)&xp[(((rp*4) + shi)*64 + slot)*8]     = hi;
    *(f16x8*)&xp[(((rp*4) + 2 + shi)*64 + slot)*8] = lo;
  }

  // per-lane x2 for the 16 (rt, reg) row instances
  float x2v[16];
#pragma unroll
  for (int rt = 0; rt < 4; ++rt)
#pragma unroll
    for (int reg = 0; reg < 4; ++reg)
      x2v[rt*4+reg] = ws[WS_X2 + row0 + rg*64 + rt*16 + quad*4 + reg];

  float best[16]; int bestk[16];
#pragma unroll
  for (int i = 0; i < 16; ++i) { best[i] = INFINITY; bestk[i] = 0; }

  f16x8 a[4][4];   // A-frags: [rt][s], loaded once after first barrier

  for (int c = 0; c < 32; ++c) {
    const int k0 = c * 256;
    // ---- convert W chunk into fragment layout ----
    if (t < 256) w2s[t] = ws[WS_W2 + k0 + t];
#pragma unroll
    for (int it = 0; it < 4; ++it) {
      const int u  = t + 512*it;        // < 2048 granules
      const int cp = u >> 7, n = (u >> 3) & 15, g = u & 7;
      const float* src = wg + (size_t)(k0 + cp*16 + n)*64 + g*8;
      float4 v0 = *(const float4*)src, v1 = *(const float4*)(src + 4);
      float vv[8] = {v0.x,v0.y,v0.z,v0.w,v1.x,v1.y,v1.z,v1.w};
      f16x8 hi, lo;
#pragma unroll
      for (int j = 0; j < 8; ++j) { _Float16 h, l; split_f16(vv[j], h, l); hi[j]=h; lo[j]=l; }
      const int slot = (g&3)*16 + n, shi = g >> 2;
      *(f16x8*)&wp[(((cp*4) + shi)*64 + slot)*8]     = hi;
      *(f16x8*)&wp[(((cp*4) + 2 + shi)*64 + slot)*8] = lo;
    }
    __syncthreads();

    if (c == 0) {   // wave-uniform; xp is stable from here on
#pragma unroll
      for (int rt = 0; rt < 4; ++rt)
#pragma unroll
        for (int s = 0; s < 4; ++s)
          a[rt][s] = *(const f16x8*)&xp[((((rg*4+rt)*4) + s)*64 + lane)*8];
    }

    // ---- MFMA phase: wave computes 64 rows x 64 codes ----
    f32x4 acc[4][4];
#pragma unroll
    for (int i = 0; i < 4; ++i)
#pragma unroll
      for (int j = 0; j < 4; ++j) acc[i][j] = (f32x4){0.f,0.f,0.f,0.f};

#pragma unroll
    for (int ct = 0; ct < 4; ++ct) {
      const int cpb = (cg*4 + ct)*4;
      f16x8 b0 = *(const f16x8*)&wp[((cpb+0)*64 + lane)*8];
      f16x8 b1 = *(const f16x8*)&wp[((cpb+1)*64 + lane)*8];
      f16x8 b2 = *(const f16x8*)&wp[((cpb+2)*64 + lane)*8];
      f16x8 b3 = *(const f16x8*)&wp[((cpb+3)*64 + lane)*8];
      // (hi+lo)x * (hi+lo)w -- 8 terms, rt-interleaved for dep distance
#pragma unroll
      for (int rt = 0; rt < 4; ++rt) acc[rt][ct] = __builtin_amdgcn_mfma_f32_16x16x32_f16(a[rt][0], b0, acc[rt][ct], 0,0,0);
#pragma unroll
      for (int rt = 0; rt < 4; ++rt) acc[rt][ct] = __builtin_amdgcn_mfma_f32_16x16x32_f16(a[rt][1], b1, acc[rt][ct], 0,0,0);
#pragma unroll
      for (int rt = 0; rt < 4; ++rt) acc[rt][ct] = __builtin_amdgcn_mfma_f32_16x16x32_f16(a[rt][2], b0, acc[rt][ct], 0,0,0);
#pragma unroll
      for (int rt = 0; rt < 4; ++rt) acc[rt][ct] = __builtin_amdgcn_mfma_f32_16x16x32_f16(a[rt][3], b1, acc[rt][ct], 0,0,0);
#pragma unroll
      for (int rt = 0; rt < 4; ++rt) acc[rt][ct] = __builtin_amdgcn_mfma_f32_16x16x32_f16(a[rt][0], b2, acc[rt][ct], 0,0,0);
#pragma unroll
      for (int rt = 0; rt < 4; ++rt) acc[rt][ct] = __builtin_amdgcn_mfma_f32_16x16x32_f16(a[rt][1], b3, acc[rt][ct], 0,0,0);
#pragma unroll
      for (int rt = 0; rt < 4; ++rt) acc[rt][ct] = __builtin_amdgcn_mfma_f32_16x16x32_f16(a[rt][2], b2, acc[rt][ct], 0,0,0);
#pragma unroll
      for (int rt = 0; rt < 4; ++rt) acc[rt][ct] = __builtin_amdgcn_mfma_f32_16x16x32_f16(a[rt][3], b3, acc[rt][ct], 0,0,0);
    }

    // ---- epilogue: distances + running argmin ----
#pragma unroll
    for (int ct = 0; ct < 4; ++ct) {
      const float w2c = w2s[cg*64 + ct*16 + n16];
      const int kk = k0 + cg*64 + ct*16 + n16;
#pragma unroll
      for (int rt = 0; rt < 4; ++rt)
#pragma unroll
        for (int reg = 0; reg < 4; ++reg) {
          const float dist = fmaf(-2.0f, acc[rt][ct][reg], __fadd_rn(x2v[rt*4+reg], w2c));
          const int bi = rt*4 + reg;
          if (dist < best[bi]) { best[bi] = dist; bestk[bi] = kk; }  // strict <, k ascending
        }
    }
    __syncthreads();  // wp/w2s free for next chunk
  }

  // ---- cross-lane merge within 16-lane col groups (lexicographic (d,k)) ----
#pragma unroll
  for (int bi = 0; bi < 16; ++bi) {
    float bd = best[bi]; int bk = bestk[bi];
#pragma unroll
    for (int m = 1; m < 16; m <<= 1) {
      const float od = __shfl_xor(bd, m, 64);
      const int   ok = __shfl_xor(bk, m, 64);
      if (od < bd || (od == bd && ok < bk)) { bd = od; bk = ok; }
    }
    best[bi] = bd; bestk[bi] = bk;
  }
  if (n16 == 0) {
#pragma unroll
    for (int rt = 0; rt < 4; ++rt)
#pragma unroll
      for (int reg = 0; reg < 4; ++reg) {
        const int row = rg*64 + rt*16 + quad*4 + reg;
        md[row*4 + cg] = best[rt*4+reg];
        mk[row*4 + cg] = bestk[rt*4+reg];
      }
  }
  __syncthreads();

  if (t < 128) {
    const int row = t;
    float bd = md[row*4]; int bk = mk[row*4];
#pragma unroll
    for (int u = 1; u < 4; ++u) {
      const float d2 = md[row*4 + u]; const int k2 = mk[row*4 + u];
      if (d2 < bd || (d2 == bd && k2 < bk)) { bd = d2; bk = k2; }
    }
    out[OUT_IDX + row0 + row] = (float)bk;
    ((int*)ws)[WS_IDX + row0 + row] = bk;
    bkL[row] = bk;
    atomicAdd(&ws[WS_COUNTS + bk], 1.0f);
  }
  __syncthreads();

  // ---- EMA segment-sum atomics (x re-read from global, coalesced) ----
#pragma unroll 4
  for (int r8 = 0; r8 < 16; ++r8) {
    const int row = r8*8 + (t >> 6);
    const int d = t & 63;
    const int bk = bkL[row];
    atomicAdd(&ws[WS_EMB + (size_t)bk*64 + d], xg[(size_t)(row0 + row)*64 + d]);
  }
}

__global__ __launch_bounds__(256) void stats_kernel(const float* __restrict__ cc,
                                                    float* __restrict__ out,
                                                    float* __restrict__ ws) {
  const int k = blockIdx.x * 256 + threadIdx.x;
  const float cnt = ws[WS_COUNTS + k];
  const float ncc = __fadd_rn(__fmul_rn(DECAYF, cc[k]), __fmul_rn(OMDF, cnt));
  out[OUT_NCC + k] = ncc;
  const float p = cnt * (1.0f/32768.0f);
  const float ent = __fmul_rn(p, logf(__fadd_rn(p, 1e-10f)));
  float v1 = ncc, v2 = ent;
#pragma unroll
  for (int off = 32; off > 0; off >>= 1) {
    v1 += __shfl_down(v1, off);
    v2 += __shfl_down(v2, off);
  }
  __shared__ float s1[4], s2[4];
  const int lane = threadIdx.x & 63, wid = threadIdx.x >> 6;
  if (lane == 0) { s1[wid] = v1; s2[wid] = v2; }
  __syncthreads();
  if (threadIdx.x == 0) {
    atomicAdd(&ws[WS_N],   (s1[0]+s1[1]) + (s1[2]+s1[3]));
    atomicAdd(&ws[WS_ENT], (s2[0]+s2[1]) + (s2[2]+s2[3]));
  }
}

__global__ __launch_bounds__(256) void update_kernel(const float* __restrict__ ws0,
                                                     float* __restrict__ out,
                                                     float* __restrict__ ws) {
  const int e = blockIdx.x * 256 + threadIdx.x;  // < 524288
  const int k = e >> 6;
  const float nws = __fadd_rn(__fmul_rn(DECAYF, ws0[e]), __fmul_rn(OMDF, ws[WS_EMB + e]));
  out[OUT_NWS + e] = nws;
  const float n = ws[WS_N];
  const float ncc = out[OUT_NCC + k];
  const float smoothed = __fmul_rn(__fadd_rn(ncc, 1e-5f) / __fadd_rn(n, 0.08192f), n);
  out[OUT_NW + e] = nws / smoothed;
}

__global__ __launch_bounds__(256) void quant_kernel(const float* __restrict__ xg,
                                                    float* __restrict__ out,
                                                    float* __restrict__ ws) {
  const int e = blockIdx.x * 256 + threadIdx.x;  // < 2097152
  const int row = e >> 6, d = e & 63;
  const int k = ((const int*)ws)[WS_IDX + row];
  const float q = out[OUT_NW + (size_t)k*64 + d];
  const float x = xg[e];
  const float df = __fsub_rn(q, x);
  out[OUT_Q + e] = __fadd_rn(x, df);
  float v = __fmul_rn(df, df);
#pragma unroll
  for (int off = 32; off > 0; off >>= 1) v += __shfl_down(v, off);
  __shared__ float sm[4];
  const int lane = threadIdx.x & 63, wid = threadIdx.x >> 6;
  if (lane == 0) sm[wid] = v;
  __syncthreads();
  if (threadIdx.x == 0) atomicAdd(&ws[WS_LOSS], (sm[0]+sm[1]) + (sm[2]+sm[3]));
}

__global__ void final_kernel(float* __restrict__ out, const float* __restrict__ ws) {
  out[OUT_LOSS] = __fmul_rn(0.25f, ws[WS_LOSS] / 2097152.0f);
  out[OUT_PERP] = expf(-ws[WS_ENT]);
}

extern "C" void kernel_launch(void* const* d_in, const int* in_sizes, int n_in,
                              void* d_out, int out_size, void* d_ws, size_t ws_size,
                              hipStream_t stream) {
  (void)in_sizes; (void)n_in; (void)out_size; (void)ws_size;
  const float* x   = (const float*)d_in[0];
  const float* w   = (const float*)d_in[1];
  const float* cc  = (const float*)d_in[2];
  const float* ws0 = (const float*)d_in[3];
  float* out = (float*)d_out;
  float* ws  = (float*)d_ws;

  hipMemsetAsync(d_ws, 0, (size_t)WS_ZERO_UNITS * 4, stream);
  hipLaunchKernelGGL(prep_kernel,   dim3(160),  dim3(256), 0, stream, x, w, ws);
  hipLaunchKernelGGL(argmin_kernel, dim3(256),  dim3(512), 0, stream, x, w, out, ws);
  hipLaunchKernelGGL(stats_kernel,  dim3(32),   dim3(256), 0, stream, cc, out, ws);
  hipLaunchKernelGGL(update_kernel, dim3(2048), dim3(256), 0, stream, ws0, out, ws);
  hipLaunchKernelGGL(quant_kernel,  dim3(8192), dim3(256), 0, stream, x, out, ws);
  hipLaunchKernelGGL(final_kernel,  dim3(1),    dim3(1),   0, stream, out, ws);
}